// Round 1
// baseline (519.814 us; speedup 1.0000x reference)
//
#include <hip/hip_runtime.h>

#define S_LEN 4096
#define D_DIM 64
#define NBH   64   // B*H = 4*16
#define EPS_F 1e-6f

__device__ __forceinline__ float phi_f(float x) {
    // elu(x)+1 == x>0 ? x+1 : exp(x)
    return x > 0.0f ? x + 1.0f : __expf(x);
}

// ---------------------------------------------------------------------------
// Mask dtype detector: scan first 4096 u32 words (16 KB — safe under byte-bool
// (16384 B), int32 (64 KB) and float32 (64 KB) interpretations).
//   all words in {0,1}            -> int32  (flag 0)
//   all words in {0,0x3F800000}   -> float  (flag 2)
//   else                          -> bytes  (flag 1)
// ---------------------------------------------------------------------------
__global__ void detect_mask(const unsigned int* __restrict__ w,
                            unsigned int* __restrict__ flag) {
    __shared__ int all01, allf;
    if (threadIdx.x == 0) { all01 = 1; allf = 1; }
    __syncthreads();
    int a = 1, f = 1;
    for (int i = threadIdx.x; i < 4096; i += blockDim.x) {
        unsigned int v = w[i];
        if (v > 1u) a = 0;
        if (v != 0u && v != 0x3F800000u) f = 0;
    }
    if (!a) atomicExch(&all01, 0);
    if (!f) atomicExch(&allf, 0);
    __syncthreads();
    if (threadIdx.x == 0) *flag = all01 ? 0u : (allf ? 2u : 1u);
}

// ---------------------------------------------------------------------------
// Phase 1: KV[bh][d][f] = sum_s phi(K)[s,d]*V[s,f] (masked), ksum[bh][d].
// Grid (64, 8): bh x s-chunk(512 rows). Block 256 = 4 waves.
// Per 32-row LDS tile each wave computes 8 rows into its private 8x8-per-lane
// register tile; block atomically adds into workspace at the end.
// ---------------------------------------------------------------------------
__global__ __launch_bounds__(256) void la_phase1(
    const float* __restrict__ K, const float* __restrict__ V,
    const void* __restrict__ mask, const unsigned int* __restrict__ flagp,
    float* __restrict__ kv_ws, float* __restrict__ ksum_ws)
{
    __shared__ float kt[32][64];
    __shared__ float vt[32][64];

    const int bh   = blockIdx.x;
    const int b    = bh >> 4;             // H = 16
    const unsigned int flag = *flagp;
    const int tid  = threadIdx.x;
    const int wave = tid >> 6;
    const int lane = tid & 63;
    const int tt   = lane >> 3;           // d-octet
    const int tf   = lane & 7;            // f-octet
    const int s0   = blockIdx.y * (S_LEN / 8);

    const float* Kbh = K + (size_t)bh * S_LEN * D_DIM;
    const float* Vbh = V + (size_t)bh * S_LEN * D_DIM;
    const int*           mi = (const int*)mask;
    const unsigned char* mb = (const unsigned char*)mask;
    const float*         mf = (const float*)mask;

    float acc[8][8];
    float ks[8];
    #pragma unroll
    for (int i = 0; i < 8; ++i) {
        ks[i] = 0.0f;
        #pragma unroll
        for (int j = 0; j < 8; ++j) acc[i][j] = 0.0f;
    }

    for (int ts = 0; ts < S_LEN / 8; ts += 32) {
        // ---- stage 32 rows of K (phi+mask) and V (mask), coalesced f4 ----
        #pragma unroll
        for (int p = 0; p < 2; ++p) {
            int fi  = p * 256 + tid;      // float4 index 0..511
            int row = fi >> 4;
            int col = (fi & 15) * 4;
            int s   = s0 + ts + row;
            int ml  = b * S_LEN + s;
            bool pad;
            if (flag == 0u)      pad = (mi[ml] != 0);
            else if (flag == 1u) pad = (mb[ml] != 0);
            else                 pad = (mf[ml] != 0.0f);
            float4 k4 = *reinterpret_cast<const float4*>(&Kbh[(size_t)s * D_DIM + col]);
            float4 v4 = *reinterpret_cast<const float4*>(&Vbh[(size_t)s * D_DIM + col]);
            if (pad) {
                k4 = make_float4(0.f, 0.f, 0.f, 0.f);
                v4 = make_float4(0.f, 0.f, 0.f, 0.f);
            } else {
                k4.x = phi_f(k4.x); k4.y = phi_f(k4.y);
                k4.z = phi_f(k4.z); k4.w = phi_f(k4.w);
            }
            *reinterpret_cast<float4*>(&kt[row][col]) = k4;
            *reinterpret_cast<float4*>(&vt[row][col]) = v4;
        }
        __syncthreads();
        // ---- each wave: 8 rows, 64 FMA per row per lane ----
        #pragma unroll
        for (int r = 0; r < 8; ++r) {
            const int row = wave * 8 + r;
            float kk[8], vv[8];
            *reinterpret_cast<float4*>(&kk[0]) = *reinterpret_cast<const float4*>(&kt[row][tt * 8]);
            *reinterpret_cast<float4*>(&kk[4]) = *reinterpret_cast<const float4*>(&kt[row][tt * 8 + 4]);
            *reinterpret_cast<float4*>(&vv[0]) = *reinterpret_cast<const float4*>(&vt[row][tf * 8]);
            *reinterpret_cast<float4*>(&vv[4]) = *reinterpret_cast<const float4*>(&vt[row][tf * 8 + 4]);
            #pragma unroll
            for (int i = 0; i < 8; ++i) {
                #pragma unroll
                for (int j = 0; j < 8; ++j)
                    acc[i][j] = fmaf(kk[i], vv[j], acc[i][j]);
                ks[i] += kk[i];
            }
        }
        __syncthreads();
    }

    float* kvo = kv_ws + (size_t)bh * D_DIM * D_DIM;
    #pragma unroll
    for (int i = 0; i < 8; ++i)
        #pragma unroll
        for (int j = 0; j < 8; ++j)
            atomicAdd(&kvo[(tt * 8 + i) * D_DIM + tf * 8 + j], acc[i][j]);
    if (tf == 0) {
        #pragma unroll
        for (int i = 0; i < 8; ++i)
            atomicAdd(&ksum_ws[bh * D_DIM + tt * 8 + i], ks[i]);
    }
}

// ---------------------------------------------------------------------------
// Phase 2: out[t] = (phi(q)[t] @ KV) / (phi(q)[t].ksum + eps).
// Grid (64, 32): bh x t-chunk(128). Block 128 = 2 waves, each wave owns 64 t.
// q staged in LDS with XOR swizzle (d ^= (t&7)*8) so the strided-t b128 reads
// are conflict-free; KV rows read with broadcast across tt. 8t x 8f per lane.
// ---------------------------------------------------------------------------
__global__ __launch_bounds__(128) void la_phase2(
    const float* __restrict__ Q,
    const float* __restrict__ kv_ws, const float* __restrict__ ksum_ws,
    float* __restrict__ out)
{
    __shared__ float qs[2][64][64];   // [wave][t_local][d swizzled]
    __shared__ float kvs[64][64];     // [d][f]

    const int bh   = blockIdx.x;
    const int tid  = threadIdx.x;     // 0..127
    const int wave = tid >> 6;
    const int lane = tid & 63;
    const int tt   = lane >> 3;       // t-phase within octet-stride
    const int tf   = lane & 7;        // f-octet
    const int t0   = blockIdx.y * 128;

    const float* Qbh = Q + (size_t)bh * S_LEN * D_DIM;
    const float* kvb = kv_ws + (size_t)bh * D_DIM * D_DIM;

    // stage KV (4096 floats)
    #pragma unroll
    for (int p = 0; p < 8; ++p) {
        int fi = p * 128 + tid;       // float4 idx 0..1023
        float4 v = *reinterpret_cast<const float4*>(&kvb[fi * 4]);
        *reinterpret_cast<float4*>(&kvs[fi >> 4][(fi & 15) * 4]) = v;
    }
    // stage phi(q), swizzled (2048 float4)
    #pragma unroll
    for (int p = 0; p < 16; ++p) {
        int fi = p * 128 + tid;
        int t  = fi >> 4;             // 0..127
        int dq = (fi & 15) * 4;
        float4 qv = *reinterpret_cast<const float4*>(&Qbh[(size_t)(t0 + t) * D_DIM + dq]);
        qv.x = phi_f(qv.x); qv.y = phi_f(qv.y);
        qv.z = phi_f(qv.z); qv.w = phi_f(qv.w);
        int dsw = dq ^ ((t & 7) * 8);
        *reinterpret_cast<float4*>(&qs[t >> 6][t & 63][dsw]) = qv;
    }
    __syncthreads();

    const float* ksb = ksum_ws + bh * D_DIM;
    float acc[8][8];
    float z[8];
    #pragma unroll
    for (int r = 0; r < 8; ++r) {
        z[r] = 0.0f;
        #pragma unroll
        for (int c = 0; c < 8; ++c) acc[r][c] = 0.0f;
    }

    for (int dq = 0; dq < 64; dq += 4) {
        float ks4[4];
        *reinterpret_cast<float4*>(&ks4[0]) = *reinterpret_cast<const float4*>(&ksb[dq]); // uniform -> SGPR
        float kvr[4][8];
        #pragma unroll
        for (int j = 0; j < 4; ++j) {
            *reinterpret_cast<float4*>(&kvr[j][0]) = *reinterpret_cast<const float4*>(&kvs[dq + j][tf * 8]);
            *reinterpret_cast<float4*>(&kvr[j][4]) = *reinterpret_cast<const float4*>(&kvs[dq + j][tf * 8 + 4]);
        }
        const int dsw = dq ^ (tt * 8);
        #pragma unroll
        for (int r = 0; r < 8; ++r) {
            float qv[4];
            *reinterpret_cast<float4*>(&qv[0]) =
                *reinterpret_cast<const float4*>(&qs[wave][tt + 8 * r][dsw]);
            z[r] = fmaf(qv[0], ks4[0], fmaf(qv[1], ks4[1],
                   fmaf(qv[2], ks4[2], fmaf(qv[3], ks4[3], z[r]))));
            #pragma unroll
            for (int j = 0; j < 4; ++j)
                #pragma unroll
                for (int c = 0; c < 8; ++c)
                    acc[r][c] = fmaf(qv[j], kvr[j][c], acc[r][c]);
        }
    }

    #pragma unroll
    for (int r = 0; r < 8; ++r) {
        int t = t0 + wave * 64 + tt + 8 * r;
        float inv = 1.0f / (z[r] + EPS_F);
        float o[8];
        #pragma unroll
        for (int c = 0; c < 8; ++c) o[c] = acc[r][c] * inv;
        float* op = out + ((size_t)bh * S_LEN + t) * D_DIM + tf * 8;
        *reinterpret_cast<float4*>(&op[0]) = *reinterpret_cast<const float4*>(&o[0]);
        *reinterpret_cast<float4*>(&op[4]) = *reinterpret_cast<const float4*>(&o[4]);
    }
}

// ---------------------------------------------------------------------------
extern "C" void kernel_launch(void* const* d_in, const int* in_sizes, int n_in,
                              void* d_out, int out_size, void* d_ws, size_t ws_size,
                              hipStream_t stream)
{
    (void)in_sizes; (void)n_in; (void)out_size; (void)ws_size;
    const float* Q   = (const float*)d_in[0];
    const float* K   = (const float*)d_in[1];
    const float* V   = (const float*)d_in[2];
    const void* mask = d_in[3];

    float* kv_ws   = (float*)d_ws;                                  // 64*4096 floats
    float* ksum_ws = kv_ws + (size_t)NBH * D_DIM * D_DIM;           // 64*64 floats
    unsigned int* flag = (unsigned int*)(ksum_ws + NBH * D_DIM);

    const size_t clear_bytes =
        ((size_t)NBH * D_DIM * D_DIM + (size_t)NBH * D_DIM) * sizeof(float);
    hipMemsetAsync(d_ws, 0, clear_bytes, stream);
    detect_mask<<<1, 256, 0, stream>>>((const unsigned int*)mask, flag);
    la_phase1<<<dim3(NBH, 8), 256, 0, stream>>>(K, V, mask, flag, kv_ws, ksum_ws);
    la_phase2<<<dim3(NBH, 32), 128, 0, stream>>>(Q, kv_ws, ksum_ws, (float*)d_out);
}

// Round 3
// 305.508 us; speedup vs baseline: 1.7015x; 1.7015x over previous
//
#include <hip/hip_runtime.h>

#define S_LEN 4096
#define D_DIM 64
#define NBH   64   // B*H = 4*16
#define EPS_F 1e-6f
#define PSZ   (D_DIM * D_DIM + D_DIM)   // 4160 floats per block partial (KV + ksum)

__device__ __forceinline__ float phi_f(float x) {
    // elu(x)+1 == x>0 ? x+1 : exp(x)
    return x > 0.0f ? x + 1.0f : __expf(x);
}

// ---------------------------------------------------------------------------
// Mask dtype detector: scan first 4096 u32 words (16 KB — safe under byte-bool
// (16384 B), int32 (64 KB) and float32 (64 KB) interpretations).
//   all words in {0,1}            -> int32 semantics (flag 0)
//   all words in {0,0x3F800000}   -> float (flag 2)
//   else                          -> bytes (flag 1)
// Note int-interpretation of float 0.0/1.0 gives the same booleans, so the
// only ambiguous cases are self-consistent.
// ---------------------------------------------------------------------------
__global__ void detect_mask(const unsigned int* __restrict__ w,
                            unsigned int* __restrict__ flag) {
    __shared__ int all01, allf;
    if (threadIdx.x == 0) { all01 = 1; allf = 1; }
    __syncthreads();
    int a = 1, f = 1;
    for (int i = threadIdx.x; i < 4096; i += blockDim.x) {
        unsigned int v = w[i];
        if (v > 1u) a = 0;
        if (v != 0u && v != 0x3F800000u) f = 0;
    }
    if (!a) atomicExch(&all01, 0);
    if (!f) atomicExch(&allf, 0);
    __syncthreads();
    if (threadIdx.x == 0) *flag = all01 ? 0u : (allf ? 2u : 1u);
}

// ---------------------------------------------------------------------------
// Phase 1: per-block partial KV[d][f] = sum_s phi(K)[s,d]*V[s,f] (masked) and
// partial ksum[d], over a chunk of S. NO global atomics: 4 waves reduce
// through LDS, then one coalesced 16.6 KB store per block into d_ws.
// Grid (64, CH). Block 256 = 4 waves. Global loads for tile i+1 are issued
// before computing tile i (register prefetch) so HBM latency hides under FMA.
// ---------------------------------------------------------------------------
__global__ __launch_bounds__(256) void la_phase1(
    const float* __restrict__ K, const float* __restrict__ V,
    const void* __restrict__ mask, const unsigned int* __restrict__ flagp,
    float* __restrict__ partials, int CH)
{
    __shared__ float smem[2 * 32 * 64];   // kt = smem[0..2048), vt = smem[2048..4096)
    __shared__ float ksred[4][64];

    const int bh   = blockIdx.x;
    const int b    = bh >> 4;             // H = 16
    const unsigned int flag = *flagp;
    const int tid  = threadIdx.x;
    const int wave = tid >> 6;
    const int lane = tid & 63;
    const int tt   = lane >> 3;           // d-octet
    const int tf   = lane & 7;            // f-octet
    const int chunk = S_LEN / CH;
    const int NT    = chunk / 32;
    const int s0    = blockIdx.y * chunk;

    const float* Kbh = K + (size_t)bh * S_LEN * D_DIM;
    const float* Vbh = V + (size_t)bh * S_LEN * D_DIM;
    const int*           mi = (const int*)mask;
    const unsigned char* mb = (const unsigned char*)mask;
    const float*         mf = (const float*)mask;

    float acc[8][8];
    float ks[8];
    #pragma unroll
    for (int i = 0; i < 8; ++i) {
        ks[i] = 0.0f;
        #pragma unroll
        for (int j = 0; j < 8; ++j) acc[i][j] = 0.0f;
    }

    const int row0 = tid >> 4;            // 0..15 (p adds 16)
    const int col0 = (tid & 15) * 4;

    float4 kr[2], vr[2];
    int    pr[2];

    // issue global loads for tile starting at s0+ts into registers
    auto issue = [&](int ts) {
        #pragma unroll
        for (int p = 0; p < 2; ++p) {
            int row = p * 16 + row0;
            int s   = s0 + ts + row;
            int ml  = b * S_LEN + s;
            bool pad;
            if (flag == 0u)      pad = (mi[ml] != 0);
            else if (flag == 1u) pad = (mb[ml] != 0);
            else                 pad = (mf[ml] != 0.0f);
            pr[p] = pad ? 1 : 0;
            kr[p] = *reinterpret_cast<const float4*>(&Kbh[(size_t)s * D_DIM + col0]);
            vr[p] = *reinterpret_cast<const float4*>(&Vbh[(size_t)s * D_DIM + col0]);
        }
    };

    issue(0);
    for (int it = 0; it < NT; ++it) {
        // regs -> LDS (phi + mask applied here)
        #pragma unroll
        for (int p = 0; p < 2; ++p) {
            int row = p * 16 + row0;
            float4 k4 = kr[p], v4 = vr[p];
            if (pr[p]) {
                k4 = make_float4(0.f, 0.f, 0.f, 0.f);
                v4 = make_float4(0.f, 0.f, 0.f, 0.f);
            } else {
                k4.x = phi_f(k4.x); k4.y = phi_f(k4.y);
                k4.z = phi_f(k4.z); k4.w = phi_f(k4.w);
            }
            *reinterpret_cast<float4*>(&smem[row * 64 + col0])        = k4;
            *reinterpret_cast<float4*>(&smem[2048 + row * 64 + col0]) = v4;
        }
        __syncthreads();
        if (it + 1 < NT) issue((it + 1) * 32);   // prefetch next tile
        // each wave: 8 rows, 8x8 FMA per row per lane
        #pragma unroll
        for (int r = 0; r < 8; ++r) {
            const int row = wave * 8 + r;
            float kk[8], vv[8];
            *reinterpret_cast<float4*>(&kk[0]) = *reinterpret_cast<const float4*>(&smem[row * 64 + tt * 8]);
            *reinterpret_cast<float4*>(&kk[4]) = *reinterpret_cast<const float4*>(&smem[row * 64 + tt * 8 + 4]);
            *reinterpret_cast<float4*>(&vv[0]) = *reinterpret_cast<const float4*>(&smem[2048 + row * 64 + tf * 8]);
            *reinterpret_cast<float4*>(&vv[4]) = *reinterpret_cast<const float4*>(&smem[2048 + row * 64 + tf * 8 + 4]);
            #pragma unroll
            for (int i = 0; i < 8; ++i) {
                #pragma unroll
                for (int j = 0; j < 8; ++j)
                    acc[i][j] = fmaf(kk[i], vv[j], acc[i][j]);
                ks[i] += kk[i];
            }
        }
        __syncthreads();
    }

    // ---- cross-wave reduction through LDS (reuse smem), then one store ----
    if (tf == 0) {
        #pragma unroll
        for (int i = 0; i < 8; ++i) ksred[wave][tt * 8 + i] = ks[i];
    }
    for (int w = 0; w < 4; ++w) {
        if (wave == w) {
            #pragma unroll
            for (int i = 0; i < 8; ++i) {
                float4* p0 = reinterpret_cast<float4*>(&smem[(tt * 8 + i) * 64 + tf * 8]);
                float4 a0 = make_float4(acc[i][0], acc[i][1], acc[i][2], acc[i][3]);
                float4 a1 = make_float4(acc[i][4], acc[i][5], acc[i][6], acc[i][7]);
                if (w == 0) { p0[0] = a0; p0[1] = a1; }
                else {
                    float4 c0 = p0[0], c1 = p0[1];
                    c0.x += a0.x; c0.y += a0.y; c0.z += a0.z; c0.w += a0.w;
                    c1.x += a1.x; c1.y += a1.y; c1.z += a1.z; c1.w += a1.w;
                    p0[0] = c0; p0[1] = c1;
                }
            }
        }
        __syncthreads();
    }

    float* pp = partials + ((size_t)(bh * CH + blockIdx.y)) * PSZ;
    #pragma unroll
    for (int q = 0; q < 4; ++q) {
        int fi = q * 256 + tid;           // float4 idx 0..1023
        reinterpret_cast<float4*>(pp)[fi] = reinterpret_cast<float4*>(smem)[fi];
    }
    if (tid < 64)
        pp[4096 + tid] = ksred[0][tid] + ksred[1][tid] + ksred[2][tid] + ksred[3][tid];
}

// ---------------------------------------------------------------------------
// Reduce CH partials per bh into final KV (64x64) and ksum (64).
// ---------------------------------------------------------------------------
__global__ __launch_bounds__(256) void la_reduce(
    const float* __restrict__ partials, float* __restrict__ kv,
    float* __restrict__ ksum, int CH)
{
    const int bh = blockIdx.x;
    const float4* base = reinterpret_cast<const float4*>(partials + (size_t)bh * CH * PSZ);
    for (int idx = threadIdx.x; idx < PSZ / 4; idx += 256) {
        float4 s = make_float4(0.f, 0.f, 0.f, 0.f);
        for (int c = 0; c < CH; ++c) {
            float4 v = base[(size_t)c * (PSZ / 4) + idx];
            s.x += v.x; s.y += v.y; s.z += v.z; s.w += v.w;
        }
        if (idx < 1024)
            reinterpret_cast<float4*>(kv + (size_t)bh * 4096)[idx] = s;
        else
            reinterpret_cast<float4*>(ksum + bh * 64)[idx - 1024] = s;
    }
}

// ---------------------------------------------------------------------------
// Phase 2: out[t] = (phi(q)[t] @ KV) / (phi(q)[t].ksum + eps).
// Grid (64, 32): bh x t-chunk(128). Block 128 = 2 waves, each wave owns 64 t.
// q staged in LDS with XOR swizzle (d ^= (t&7)*8); ksum staged in LDS (was a
// per-iteration global load — the round-1 stall suspect). 8t x 8f per lane.
// ---------------------------------------------------------------------------
__global__ __launch_bounds__(128) void la_phase2(
    const float* __restrict__ Q,
    const float* __restrict__ kv_ws, const float* __restrict__ ksum_ws,
    float* __restrict__ out)
{
    __shared__ float qs[2][64][64];   // [wave][t_local][d swizzled]
    __shared__ float kvs[64][64];     // [d][f]
    __shared__ float kss[64];

    const int bh   = blockIdx.x;
    const int tid  = threadIdx.x;     // 0..127
    const int wave = tid >> 6;
    const int lane = tid & 63;
    const int tt   = lane >> 3;       // t-phase within octet-stride
    const int tf   = lane & 7;        // f-octet
    const int t0   = blockIdx.y * 128;

    const float* Qbh = Q + (size_t)bh * S_LEN * D_DIM;
    const float* kvb = kv_ws + (size_t)bh * D_DIM * D_DIM;

    // stage KV (4096 floats)
    #pragma unroll
    for (int p = 0; p < 8; ++p) {
        int fi = p * 128 + tid;       // float4 idx 0..1023
        float4 v = *reinterpret_cast<const float4*>(&kvb[fi * 4]);
        *reinterpret_cast<float4*>(&kvs[fi >> 4][(fi & 15) * 4]) = v;
    }
    // stage ksum (64 floats)
    if (tid < 16)
        reinterpret_cast<float4*>(kss)[tid] =
            reinterpret_cast<const float4*>(ksum_ws + bh * D_DIM)[tid];
    // stage phi(q), swizzled (2048 float4)
    #pragma unroll
    for (int p = 0; p < 16; ++p) {
        int fi = p * 128 + tid;
        int t  = fi >> 4;             // 0..127
        int dq = (fi & 15) * 4;
        float4 qv = *reinterpret_cast<const float4*>(&Qbh[(size_t)(t0 + t) * D_DIM + dq]);
        qv.x = phi_f(qv.x); qv.y = phi_f(qv.y);
        qv.z = phi_f(qv.z); qv.w = phi_f(qv.w);
        int dsw = dq ^ ((t & 7) * 8);
        *reinterpret_cast<float4*>(&qs[t >> 6][t & 63][dsw]) = qv;
    }
    __syncthreads();

    float acc[8][8];
    float z[8];
    #pragma unroll
    for (int r = 0; r < 8; ++r) {
        z[r] = 0.0f;
        #pragma unroll
        for (int c = 0; c < 8; ++c) acc[r][c] = 0.0f;
    }

    #pragma unroll 4
    for (int dq = 0; dq < 64; dq += 4) {
        float ks4[4];
        *reinterpret_cast<float4*>(&ks4[0]) = *reinterpret_cast<const float4*>(&kss[dq]);
        float kvr[4][8];
        #pragma unroll
        for (int j = 0; j < 4; ++j) {
            *reinterpret_cast<float4*>(&kvr[j][0]) = *reinterpret_cast<const float4*>(&kvs[dq + j][tf * 8]);
            *reinterpret_cast<float4*>(&kvr[j][4]) = *reinterpret_cast<const float4*>(&kvs[dq + j][tf * 8 + 4]);
        }
        const int dsw = dq ^ (tt * 8);
        #pragma unroll
        for (int r = 0; r < 8; ++r) {
            float qv[4];
            *reinterpret_cast<float4*>(&qv[0]) =
                *reinterpret_cast<const float4*>(&qs[wave][tt + 8 * r][dsw]);
            z[r] = fmaf(qv[0], ks4[0], fmaf(qv[1], ks4[1],
                   fmaf(qv[2], ks4[2], fmaf(qv[3], ks4[3], z[r]))));
            #pragma unroll
            for (int j = 0; j < 4; ++j)
                #pragma unroll
                for (int c = 0; c < 8; ++c)
                    acc[r][c] = fmaf(qv[j], kvr[j][c], acc[r][c]);
        }
    }

    #pragma unroll
    for (int r = 0; r < 8; ++r) {
        int t = t0 + wave * 64 + tt + 8 * r;
        float inv = 1.0f / (z[r] + EPS_F);
        float o[8];
        #pragma unroll
        for (int c = 0; c < 8; ++c) o[c] = acc[r][c] * inv;
        float* op = out + ((size_t)bh * S_LEN + t) * D_DIM + tf * 8;
        *reinterpret_cast<float4*>(&op[0]) = *reinterpret_cast<const float4*>(&o[0]);
        *reinterpret_cast<float4*>(&op[4]) = *reinterpret_cast<const float4*>(&o[4]);
    }
}

// ---------------------------------------------------------------------------
extern "C" void kernel_launch(void* const* d_in, const int* in_sizes, int n_in,
                              void* d_out, int out_size, void* d_ws, size_t ws_size,
                              hipStream_t stream)
{
    (void)in_sizes; (void)n_in; (void)out_size;
    const float* Q   = (const float*)d_in[0];
    const float* K   = (const float*)d_in[1];
    const float* V   = (const float*)d_in[2];
    const void* mask = d_in[3];

    // ws layout: partials[NBH*CH*PSZ] | kv[NBH*4096] | ksum[NBH*64] | flag
    int CH = 16;
    while (CH > 1) {
        size_t need = ((size_t)NBH * CH * PSZ + (size_t)NBH * 4096 + NBH * 64) * 4 + 16;
        if (need <= ws_size) break;
        CH >>= 1;
    }
    float* partials = (float*)d_ws;
    float* kvf  = partials + (size_t)NBH * CH * PSZ;
    float* ksf  = kvf + (size_t)NBH * 4096;
    unsigned int* flag = (unsigned int*)(ksf + NBH * 64);

    detect_mask<<<1, 256, 0, stream>>>((const unsigned int*)mask, flag);
    la_phase1<<<dim3(NBH, CH), 256, 0, stream>>>(K, V, mask, flag, partials, CH);
    la_reduce<<<NBH, 256, 0, stream>>>(partials, kvf, ksf, CH);
    la_phase2<<<dim3(NBH, 32), 128, 0, stream>>>(Q, kvf, ksf, (float*)d_out);
}